// Round 3
// baseline (130.299 us; speedup 1.0000x reference)
//
#include <hip/hip_runtime.h>
#include <math.h>

#define BB 2
#define NN 768
#define EN 64
#define EE 16
#define FF 64
#define ROWS (BB * NN)   // 1536

// ---------------------------------------------------------------------------
// Kernel 0: we[k] = sum_f W_edge[k,f] * a_w[F+f]   (k < 16)
//           we[16] = S_c = sum_f a_w[2F+f]
// ---------------------------------------------------------------------------
__global__ __launch_bounds__(64) void prep_we(const float* __restrict__ W_edge,
                                              const float* __restrict__ a_w,
                                              float* __restrict__ we) {
    int t = threadIdx.x;
    if (t < EE) {
        float s = 0.f;
        #pragma unroll
        for (int f = 0; f < FF; ++f) s = fmaf(W_edge[t * FF + f], a_w[FF + f], s);
        we[t] = s;
    } else if (t == EE) {
        float s = 0.f;
        #pragma unroll
        for (int f = 0; f < FF; ++f) s += a_w[2 * FF + f];
        we[EE] = s;
    }
}

// ---------------------------------------------------------------------------
// Kernel 1: per row (b*N+i):  h[row,f] = nodes[row,:] @ W_node[:,f]
//           r[row] = h[row,:]·a_w[0:F]
// one block = one row, 64 threads (one wave), thread t owns f = t
// ---------------------------------------------------------------------------
__global__ __launch_bounds__(64) void node_proj(const float* __restrict__ nodes,
                                                const float* __restrict__ W_node,
                                                const float* __restrict__ a_w,
                                                float* __restrict__ h,
                                                float* __restrict__ r) {
    int row = blockIdx.x;
    int t = threadIdx.x;
    __shared__ float nd[EN];
    nd[t] = nodes[(size_t)row * EN + t];
    __syncthreads();
    float acc = 0.f;
    #pragma unroll
    for (int k = 0; k < EN; ++k) acc = fmaf(nd[k], W_node[k * FF + t], acc);
    h[(size_t)row * FF + t] = acc;
    float rv = acc * a_w[t];
    #pragma unroll
    for (int off = 32; off; off >>= 1) rv += __shfl_xor(rv, off);
    if (t == 0) r[row] = rv;
}

// ---------------------------------------------------------------------------
// Kernel 2: main. One block per (b,i) row, 256 threads.
//  s_ij = r_i + edges[b,i,j,:]·we + h[b,i, j/12]*S_c
//  aw = leaky_relu(s)*mask_i
//  att_ij = (aw>0) * exp(aw - max_j) / sum_j exp(aw - max_j)
//  out[b,i,f] = sum_j att_ij * h[b,j,f]
// ---------------------------------------------------------------------------
__global__ __launch_bounds__(256) void gat_main(const float* __restrict__ edges,
                                                const int* __restrict__ mask,
                                                const float* __restrict__ h,
                                                const float* __restrict__ r,
                                                const float* __restrict__ we_g,
                                                float* __restrict__ out) {
    const int row = blockIdx.x;          // b*N + i
    const int t = threadIdx.x;
    const int bN = (row >= NN) ? NN : 0; // base row index of this batch's columns

    __shared__ __align__(16) float we_l[EE];
    __shared__ float h_l[FF];            // h[row, :]
    __shared__ float s_aw[NN];
    __shared__ float red[8];
    __shared__ float red2[4][FF];

    if (t < EE) we_l[t] = we_g[t];
    if (t < FF) h_l[t] = h[(size_t)row * FF + t];
    const float S_c = we_g[EE];
    const float r_i = r[row];
    const float mf = mask[row] ? 1.f : 0.f;
    __syncthreads();

    // ---- phase 2: scores (fully coalesced float4 stream of the edge row) ----
    const float4* erow = (const float4*)(edges + (size_t)row * (NN * EE));
    const int g = t & 3;          // which quarter of the 16 edge features
    const int jbase = t >> 2;     // j offset within each 64-wide chunk
    const float4 wev = ((const float4*)we_l)[g];
    float mx = -INFINITY;
    #pragma unroll
    for (int k = 0; k < 12; ++k) {
        float4 ev = erow[k * 256 + t];
        float d = ev.x * wev.x + ev.y * wev.y + ev.z * wev.z + ev.w * wev.w;
        d += __shfl_xor(d, 1);
        d += __shfl_xor(d, 2);          // all 4 lanes of the group now hold the full dot
        int j = k * 64 + jbase;
        float s = r_i + h_l[j / 12] * S_c + d;
        float aw = (s > 0.f) ? s : 0.2f * s;
        aw *= mf;
        if (g == 0) s_aw[j] = aw;
        mx = fmaxf(mx, aw);
    }
    // block max
    #pragma unroll
    for (int off = 32; off; off >>= 1) mx = fmaxf(mx, __shfl_xor(mx, off));
    if ((t & 63) == 0) red[t >> 6] = mx;
    __syncthreads();
    mx = fmaxf(fmaxf(red[0], red[1]), fmaxf(red[2], red[3]));

    // ---- phase 3: exp + sum; gate numerator by adj = (aw > 0) ----
    float sum = 0.f;
    #pragma unroll
    for (int jj = 0; jj < 3; ++jj) {
        int j = jj * 256 + t;
        float aw = s_aw[j];
        float ex = expf(aw - mx);
        sum += ex;
        s_aw[j] = (aw > 0.f) ? ex : 0.f;   // gated numerator
    }
    #pragma unroll
    for (int off = 32; off; off >>= 1) sum += __shfl_xor(sum, off);
    if ((t & 63) == 0) red[4 + (t >> 6)] = sum;
    __syncthreads();
    const float inv = 1.f / (red[4] + red[5] + red[6] + red[7]);

    // ---- phase 4: out[row,f] = inv * sum_j s_aw[j] * h[bN+j, f] ----
    const int f = t & 63;
    const int ch = t >> 6;                 // 4 chunks of 192 columns
    const float* hb = h + (size_t)bN * FF;
    float acc = 0.f;
    const int j0 = ch * 192;
    #pragma unroll 4
    for (int j = j0; j < j0 + 192; ++j)
        acc = fmaf(s_aw[j], hb[(size_t)j * FF + f], acc);
    red2[ch][f] = acc;
    __syncthreads();
    if (t < FF) {
        float o = (red2[0][t] + red2[1][t] + red2[2][t] + red2[3][t]) * inv;
        out[(size_t)row * FF + t] = o;
    }
}

// ---------------------------------------------------------------------------
extern "C" void kernel_launch(void* const* d_in, const int* in_sizes, int n_in,
                              void* d_out, int out_size, void* d_ws, size_t ws_size,
                              hipStream_t stream) {
    const float* nodes  = (const float*)d_in[0];   // (B,N,EN)
    const float* edges  = (const float*)d_in[1];   // (B,N,N,EE)
    const int*   nmask  = (const int*)d_in[2];     // (B,N) bool->int32
    const float* W_node = (const float*)d_in[3];   // (EN,F)
    const float* W_edge = (const float*)d_in[4];   // (EE,F)
    const float* a_w    = (const float*)d_in[5];   // (3F,1)
    float* out = (float*)d_out;

    float* ws = (float*)d_ws;
    float* h  = ws;                       // ROWS*FF
    float* r  = h + (size_t)ROWS * FF;    // ROWS
    float* we = r + ROWS;                 // EE+1

    prep_we<<<1, 64, 0, stream>>>(W_edge, a_w, we);
    node_proj<<<ROWS, 64, 0, stream>>>(nodes, W_node, a_w, h, r);
    gat_main<<<ROWS, 256, 0, stream>>>(edges, nmask, h, r, we, out);
}

// Round 6
// 121.806 us; speedup vs baseline: 1.0697x; 1.0697x over previous
//
#include <hip/hip_runtime.h>
#include <math.h>

#define NN 768
#define EN 64
#define EE 16
#define FF 64
#define ROWS 1536   // B*N, B=2

// ---------------------------------------------------------------------------
// Kernel 1: per row: h[row,f] = nodes[row,:] @ W_node[:,f];  r[row] = h·a_row
// block 0 additionally computes we[k] = W_edge[k,:]·a_edge and S_c = Σ a_col.
// ---------------------------------------------------------------------------
__global__ __launch_bounds__(64) void node_proj(const float* __restrict__ nodes,
                                                const float* __restrict__ W_node,
                                                const float* __restrict__ W_edge,
                                                const float* __restrict__ a_w,
                                                float* __restrict__ h,
                                                float* __restrict__ r,
                                                float* __restrict__ we) {
    const int row = blockIdx.x;
    const int t = threadIdx.x;
    __shared__ float nd[EN];
    nd[t] = nodes[(size_t)row * EN + t];
    __syncthreads();
    float acc = 0.f;
    #pragma unroll
    for (int k = 0; k < EN; ++k) acc = fmaf(nd[k], W_node[k * FF + t], acc);
    h[(size_t)row * FF + t] = acc;
    float rv = acc * a_w[t];
    #pragma unroll
    for (int off = 32; off; off >>= 1) rv += __shfl_xor(rv, off);
    if (t == 0) r[row] = rv;

    if (row == 0) {                 // fused prep: we[0:16], we[16]=S_c
        if (t < EE) {
            float s = 0.f;
            #pragma unroll
            for (int f = 0; f < FF; ++f) s = fmaf(W_edge[t * FF + f], a_w[FF + f], s);
            we[t] = s;
        } else if (t == EE) {
            float s = 0.f;
            #pragma unroll
            for (int f = 0; f < FF; ++f) s += a_w[2 * FF + f];
            we[EE] = s;
        }
    }
}

// ---------------------------------------------------------------------------
// Kernel 2: main. One block per ROW PAIR (2b, 2b+1), 512 threads (8 waves).
//  waves 0-3 handle row rr=0, waves 4-7 row rr=1 for the edge stream;
//  phase 4 shares each h load between both rows (halves L2 traffic).
// ---------------------------------------------------------------------------
__global__ __launch_bounds__(512) void gat_main(const float* __restrict__ edges,
                                                const int* __restrict__ mask,
                                                const float* __restrict__ h,
                                                const float* __restrict__ r,
                                                const float* __restrict__ we_g,
                                                float* __restrict__ out) {
    const int bid = blockIdx.x;          // row pair
    const int t = threadIdx.x;
    const int rr = t >> 8;               // which row of the pair
    const int tt = t & 255;              // lane within the row team
    const int row = 2 * bid + rr;
    const int bN = (row >= NN) ? NN : 0; // column base of this batch

    __shared__ __align__(16) float we_l[EE];
    __shared__ float base_l[2][EN];      // r_i + h[row,q]*S_c  (q = j/12)
    __shared__ float s_aw[2][NN];
    __shared__ float redM[8], redS[8];
    __shared__ float redP[8][2][FF];

    if (t < EE) we_l[t] = we_g[t];
    if (t < 128) {                       // per-pair additive table
        const int pr = t >> 6, q = t & 63;
        const int prow = 2 * bid + pr;
        base_l[pr][q] = r[prow] + h[(size_t)prow * FF + q] * we_g[EE];
    }
    const float mf = (mask[row] != 0) ? 1.f : 0.f;
    __syncthreads();

    // ---- phase 2: scores — coalesced float4 stream of this row's edges ----
    const float4* erow = (const float4*)(edges + (size_t)row * (NN * EE));
    const int g = tt & 3;
    const int jbase = tt >> 2;
    const float4 wev = ((const float4*)we_l)[g];
    float mx = -INFINITY;
    #pragma unroll 4
    for (int k = 0; k < 12; ++k) {
        float4 ev = erow[k * 256 + tt];
        float d = ev.x * wev.x + ev.y * wev.y + ev.z * wev.z + ev.w * wev.w;
        d += __shfl_xor(d, 1);
        d += __shfl_xor(d, 2);           // 4-lane group now holds full 16-dot
        const int j = k * 64 + jbase;
        float s = base_l[rr][j / 12] + d;
        float aw = (s > 0.f) ? s : 0.2f * s;
        aw *= mf;
        if (g == 0) s_aw[rr][j] = aw;
        mx = fmaxf(mx, aw);
    }
    #pragma unroll
    for (int off = 32; off; off >>= 1) mx = fmaxf(mx, __shfl_xor(mx, off));
    if ((t & 63) == 0) redM[t >> 6] = mx;
    __syncthreads();
    {
        const int b = rr * 4;
        mx = fmaxf(fmaxf(redM[b], redM[b + 1]), fmaxf(redM[b + 2], redM[b + 3]));
    }

    // ---- phase 3: exp + sum; numerator gated by adj = (aw > 0) ----
    float sum = 0.f;
    #pragma unroll
    for (int jj = 0; jj < 3; ++jj) {
        const int j = jj * 256 + tt;
        const float aw = s_aw[rr][j];
        const float ex = __expf(aw - mx);
        sum += ex;
        s_aw[rr][j] = (aw > 0.f) ? ex : 0.f;
    }
    #pragma unroll
    for (int off = 32; off; off >>= 1) sum += __shfl_xor(sum, off);
    if ((t & 63) == 0) redS[t >> 6] = sum;
    __syncthreads();

    // ---- phase 4: out[row,f] = inv * Σ_j s_aw[j] * h[bN+j,f], h shared ----
    const int f = t & 63;
    const int ch = t >> 6;               // wave id = j-chunk (8 × 96)
    const float* hb = h + (size_t)bN * FF;
    float acc0 = 0.f, acc1 = 0.f;
    const int j0 = ch * 96;
    #pragma unroll 4
    for (int j = j0; j < j0 + 96; ++j) {
        const float hv = hb[(size_t)j * FF + f];
        acc0 = fmaf(s_aw[0][j], hv, acc0);
        acc1 = fmaf(s_aw[1][j], hv, acc1);
    }
    redP[ch][0][f] = acc0;
    redP[ch][1][f] = acc1;
    __syncthreads();
    if (t < 128) {
        const int pr = t >> 6, q = t & 63;
        const float inv = 1.f / (redS[pr * 4] + redS[pr * 4 + 1] +
                                 redS[pr * 4 + 2] + redS[pr * 4 + 3]);
        float o = 0.f;
        #pragma unroll
        for (int c = 0; c < 8; ++c) o += redP[c][pr][q];
        out[(size_t)(2 * bid + pr) * FF + q] = o * inv;
    }
}

// ---------------------------------------------------------------------------
extern "C" void kernel_launch(void* const* d_in, const int* in_sizes, int n_in,
                              void* d_out, int out_size, void* d_ws, size_t ws_size,
                              hipStream_t stream) {
    const float* nodes  = (const float*)d_in[0];   // (B,N,EN)
    const float* edges  = (const float*)d_in[1];   // (B,N,N,EE)
    const int*   nmask  = (const int*)d_in[2];     // (B,N) bool->int32
    const float* W_node = (const float*)d_in[3];   // (EN,F)
    const float* W_edge = (const float*)d_in[4];   // (EE,F)
    const float* a_w    = (const float*)d_in[5];   // (3F,1)
    float* out = (float*)d_out;

    float* ws = (float*)d_ws;
    float* h  = ws;                       // ROWS*FF
    float* r  = h + (size_t)ROWS * FF;    // ROWS
    float* we = r + ROWS;                 // EE+1

    node_proj<<<ROWS, 64, 0, stream>>>(nodes, W_node, W_edge, a_w, h, r, we);
    gat_main<<<ROWS / 2, 512, 0, stream>>>(edges, nmask, h, r, we, out);
}